// Round 6
// baseline (439.090 us; speedup 1.0000x reference)
//
#include <hip/hip_runtime.h>

#define D 128

typedef __attribute__((ext_vector_type(8))) short short8;
typedef __attribute__((ext_vector_type(4))) float floatx4;

__device__ __forceinline__ short f32_bf16(float f) {
    unsigned u = __builtin_bit_cast(unsigned, f);
    u += 0x7fffu + ((u >> 16) & 1u);          // RNE
    return (short)(u >> 16);
}

// physical XCD id (hwreg 20 = HW_REG_XCC_ID, bits [3:0]) — wave-uniform
__device__ __forceinline__ int xcd_id() {
    return __builtin_amdgcn_s_getreg(20 | (3 << 11)) & 7;
}

// ---------------------------------------------------------------------------
// K1: out-degree histogram, physical-XCD replicas + workgroup-scope atomics.
// Exact for ANY block->XCD placement: every atomic to replica r comes from a
// wave physically on XCD r, so the XCD-local L2 services the RMW atomically.
// ---------------------------------------------------------------------------
__global__ __launch_bounds__(256) void k_deg_s(const int* __restrict__ src,
                                               int* __restrict__ ds_rep,
                                               int E, int N) {
    int e = blockIdx.x * 256 + threadIdx.x;
    int r = xcd_id();
    if (e < E) {
        __hip_atomic_fetch_add(&ds_rep[r * N + src[e]], 1,
                               __ATOMIC_RELAXED, __HIP_MEMORY_SCOPE_WORKGROUP);
    }
}

// ---------------------------------------------------------------------------
// K2: reduce replicas -> norm_src
// ---------------------------------------------------------------------------
__global__ __launch_bounds__(256) void k_norm_s(const int* __restrict__ ds_rep,
                                                float* __restrict__ norm_src,
                                                int N) {
    int i = blockIdx.x * 256 + threadIdx.x;
    if (i < N) {
        int s = 0;
        #pragma unroll
        for (int r = 0; r < 8; ++r) s += ds_rep[r * N + i];
        norm_src[i] = rsqrtf((float)max(s, 1));
    }
}

// ---------------------------------------------------------------------------
// K3: x -> bf16 copy (halves k_agg gather traffic)
// ---------------------------------------------------------------------------
__global__ __launch_bounds__(256) void k_cvt(const float* __restrict__ x,
                                             unsigned short* __restrict__ xb,
                                             int n8) {
    int i = blockIdx.x * 256 + threadIdx.x;
    if (i < n8) {
        float4 a = ((const float4*)x)[2 * i];
        float4 b = ((const float4*)x)[2 * i + 1];
        short8 v;
        v[0] = f32_bf16(a.x); v[1] = f32_bf16(a.y);
        v[2] = f32_bf16(a.z); v[3] = f32_bf16(a.w);
        v[4] = f32_bf16(b.x); v[5] = f32_bf16(b.y);
        v[6] = f32_bf16(b.z); v[7] = f32_bf16(b.w);
        *(short8*)(xb + i * 8) = v;
    }
}

// ---------------------------------------------------------------------------
// K4: ELL fill. R=8: XCD-replicated counters (workgroup scope, serviced in
// the local L2) + per-(node,replica) 16-slot segment = one 64B line touched
// by exactly one XCD. R=1: legacy agent-scope single allocator.
// ---------------------------------------------------------------------------
template<int R, int SUBCAP>
__global__ __launch_bounds__(256) void k_fill(const int* __restrict__ src,
                                              const int* __restrict__ dst,
                                              int* __restrict__ cnt,
                                              int* __restrict__ csr,
                                              int E, int N) {
    int e = blockIdx.x * 256 + threadIdx.x;
    if (e >= E) return;
    int d = dst[e];
    if (R == 8) {
        int r = xcd_id();
        int slot = __hip_atomic_fetch_add(&cnt[r * N + d], 1,
                                          __ATOMIC_RELAXED,
                                          __HIP_MEMORY_SCOPE_WORKGROUP);
        if (slot < SUBCAP) csr[d * (R * SUBCAP) + r * SUBCAP + slot] = src[e];
    } else {
        int slot = atomicAdd(&cnt[d], 1);
        if (slot < SUBCAP) csr[d * SUBCAP + slot] = src[e];
    }
}

// ---------------------------------------------------------------------------
// K5: per-node aggregation over R segments. One wave per node; wave-uniform
// node id -> scalar csr/cnt loads; lanes gather 256B (bf16) or 512B (f32)
// rows. agg[n] = rsqrt(max(indeg,1)) * sum_e norm_src[s_e] * x[s_e]
// ---------------------------------------------------------------------------
template<int R, int SUBCAP>
__global__ __launch_bounds__(256) void k_agg(const int* __restrict__ csr,
                                             const int* __restrict__ cnt,
                                             const float* __restrict__ norm_src,
                                             const unsigned int* __restrict__ xb,
                                             const float* __restrict__ x,
                                             float* __restrict__ agg, int N) {
    const int w = __builtin_amdgcn_readfirstlane(threadIdx.x >> 6);
    const int lane = threadIdx.x & 63;
    const int n = blockIdx.x * 4 + w;
    if (n >= N) return;
    int cr[R];
    int deg = 0;
    #pragma unroll
    for (int r = 0; r < R; ++r) {
        cr[r] = cnt[r * N + n];
        deg += cr[r];
    }
    float ax = 0.f, ay = 0.f;
    if (xb) {
        #pragma unroll
        for (int r = 0; r < R; ++r) {
            int c = min(cr[r], SUBCAP);
            const int* seg = csr + n * (R * SUBCAP) + r * SUBCAP;
            int i = 0;
            for (; i + 2 <= c; i += 2) {
                int s0 = seg[i];
                int s1 = seg[i + 1];
                float a0 = norm_src[s0];
                float a1 = norm_src[s1];
                unsigned u0 = xb[s0 * 64 + lane];
                unsigned u1 = xb[s1 * 64 + lane];
                ax = fmaf(__builtin_bit_cast(float, u0 << 16), a0, ax);
                ay = fmaf(__builtin_bit_cast(float, u0 & 0xffff0000u), a0, ay);
                ax = fmaf(__builtin_bit_cast(float, u1 << 16), a1, ax);
                ay = fmaf(__builtin_bit_cast(float, u1 & 0xffff0000u), a1, ay);
            }
            if (i < c) {
                int s0 = seg[i];
                float a0 = norm_src[s0];
                unsigned u0 = xb[s0 * 64 + lane];
                ax = fmaf(__builtin_bit_cast(float, u0 << 16), a0, ax);
                ay = fmaf(__builtin_bit_cast(float, u0 & 0xffff0000u), a0, ay);
            }
        }
    } else {
        const float2* __restrict__ x2 = (const float2*)x;
        #pragma unroll
        for (int r = 0; r < R; ++r) {
            int c = min(cr[r], SUBCAP);
            const int* seg = csr + n * (R * SUBCAP) + r * SUBCAP;
            int i = 0;
            for (; i + 2 <= c; i += 2) {
                int s0 = seg[i];
                int s1 = seg[i + 1];
                float a0 = norm_src[s0];
                float a1 = norm_src[s1];
                float2 v0 = x2[s0 * 64 + lane];
                float2 v1 = x2[s1 * 64 + lane];
                ax = fmaf(v0.x, a0, ax); ay = fmaf(v0.y, a0, ay);
                ax = fmaf(v1.x, a1, ax); ay = fmaf(v1.y, a1, ay);
            }
            if (i < c) {
                int s0 = seg[i];
                float a0 = norm_src[s0];
                float2 v0 = x2[s0 * 64 + lane];
                ax = fmaf(v0.x, a0, ax); ay = fmaf(v0.y, a0, ay);
            }
        }
    }
    float nd = rsqrtf((float)max(deg, 1));
    ((float2*)agg)[n * 64 + lane] = make_float2(ax * nd, ay * nd);
}

// ---------------------------------------------------------------------------
// K6: MFMA bf16 GEMM + NodeNorm + relu + residual (unchanged).
// ---------------------------------------------------------------------------
#define WT_STRIDE 136
#define H_STRIDE  132

__global__ __launch_bounds__(256, 2) void k_gemm_norm(
    const float* __restrict__ agg,
    const float* __restrict__ x,
    const float* __restrict__ W,
    const float* __restrict__ bias,
    float* __restrict__ out, int N)
{
    __shared__ char raw[D * WT_STRIDE * 2];           // 34816 B >= 64*132*4
    short* Wt = (short*)raw;                          // Wt[c][k], bf16
    float* h  = (float*)raw;                          // h[64][H_STRIDE], after

    const int t = threadIdx.x;
    const int lane = t & 63;
    const int w = t >> 6;
    const int row0 = blockIdx.x * 64;

    #pragma unroll 4
    for (int i = 0; i < 64; ++i) {
        int idx = t + i * 256;
        int k = idx >> 7, c = idx & 127;
        Wt[c * WT_STRIDE + k] = f32_bf16(W[idx]);
    }
    __syncthreads();

    const int col16 = lane & 15;
    const int quad  = lane >> 4;
    int arow = row0 + w * 16 + col16;
    if (arow >= N) arow = N - 1;
    const float* aptr = agg + (long long)arow * D + quad * 8;

    floatx4 acc[8];
    #pragma unroll
    for (int c = 0; c < 8; ++c) {
        float b = bias[c * 16 + col16];
        acc[c] = (floatx4){b, b, b, b};
    }

    #pragma unroll
    for (int kc = 0; kc < 4; ++kc) {
        float4 a0 = *(const float4*)(aptr + kc * 32);
        float4 a1 = *(const float4*)(aptr + kc * 32 + 4);
        short8 af;
        af[0] = f32_bf16(a0.x); af[1] = f32_bf16(a0.y);
        af[2] = f32_bf16(a0.z); af[3] = f32_bf16(a0.w);
        af[4] = f32_bf16(a1.x); af[5] = f32_bf16(a1.y);
        af[6] = f32_bf16(a1.z); af[7] = f32_bf16(a1.w);
        const short* wbase = Wt + kc * 32 + quad * 8;
        #pragma unroll
        for (int c = 0; c < 8; ++c) {
            short8 bf = *(const short8*)(wbase + (c * 16 + col16) * WT_STRIDE);
            acc[c] = __builtin_amdgcn_mfma_f32_16x16x32_bf16(af, bf, acc[c], 0, 0, 0);
        }
    }
    __syncthreads();

    #pragma unroll
    for (int c = 0; c < 8; ++c) {
        #pragma unroll
        for (int i = 0; i < 4; ++i) {
            h[(w * 16 + quad * 4 + i) * H_STRIDE + c * 16 + col16] = acc[c][i];
        }
    }
    __syncthreads();

    const int row = t >> 2;
    const int part = t & 3;
    const float* hp = h + row * H_STRIDE + part * 32;
    float4 hv[8];
    float s = 0.f, ss = 0.f;
    #pragma unroll
    for (int i = 0; i < 8; ++i) {
        float4 v = *(const float4*)(hp + i * 4);
        hv[i] = v;
        s  += v.x + v.y + v.z + v.w;
        ss += v.x * v.x + v.y * v.y + v.z * v.z + v.w * v.w;
    }
    s += __shfl_xor(s, 1); ss += __shfl_xor(ss, 1);
    s += __shfl_xor(s, 2); ss += __shfl_xor(ss, 2);
    const float mean = s * (1.0f / 128.0f);
    const float var = ss * (1.0f / 128.0f) - mean * mean;
    const float inv = rsqrtf(var + 1e-5f);
    const int grow = row0 + row;
    if (grow < N) {
        const float* xp = x + (long long)grow * D + part * 32;
        float* op = out + (long long)grow * D + part * 32;
        #pragma unroll
        for (int i = 0; i < 8; ++i) {
            float4 v = hv[i];
            float4 xr = *(const float4*)(xp + i * 4);
            float4 o;
            o.x = fmaxf((v.x - mean) * inv, 0.f) + xr.x;
            o.y = fmaxf((v.y - mean) * inv, 0.f) + xr.y;
            o.z = fmaxf((v.z - mean) * inv, 0.f) + xr.z;
            o.w = fmaxf((v.w - mean) * inv, 0.f) + xr.w;
            *(float4*)(op + i * 4) = o;
        }
    }
}

// ---------------------------------------------------------------------------
extern "C" void kernel_launch(void* const* d_in, const int* in_sizes, int n_in,
                              void* d_out, int out_size, void* d_ws, size_t ws_size,
                              hipStream_t stream) {
    const float* x    = (const float*)d_in[0];
    const float* W    = (const float*)d_in[1];
    const float* bias = (const float*)d_in[2];
    const int*   src  = (const int*)d_in[3];
    const int*   dst  = (const int*)d_in[4];
    const int N = in_sizes[0] / D;
    const int E = in_sizes[3];
    float* out = (float*)d_out;

    const size_t AL = 255;
    // Tiered config: prefer replicated fill (CAPT=128), then bf16 gathers.
    size_t cnt_rep_b = (((size_t)8 * N * 4) + AL) & ~AL;
    size_t cnt_one_b = (((size_t)N * 4) + AL) & ~AL;
    size_t nsrc_b    = (((size_t)N * 4) + AL) & ~AL;
    size_t csr128_b  = (((size_t)N * 128 * 4) + AL) & ~AL;
    size_t csr64_b   = (((size_t)N * 64 * 4) + AL) & ~AL;
    size_t xb_b      = (((size_t)N * D * 2) + AL) & ~AL;

    bool use_rep, use_bf;
    if (ws_size >= cnt_rep_b + nsrc_b + csr128_b + xb_b)      { use_rep = true;  use_bf = true;  }
    else if (ws_size >= cnt_rep_b + nsrc_b + csr128_b)        { use_rep = true;  use_bf = false; }
    else if (ws_size >= cnt_one_b + nsrc_b + csr64_b + xb_b)  { use_rep = false; use_bf = true;  }
    else                                                      { use_rep = false; use_bf = false; }

    char* p = (char*)d_ws;
    size_t cnt_b = use_rep ? cnt_rep_b : cnt_one_b;
    size_t csr_b = use_rep ? csr128_b  : csr64_b;
    int*   cnt  = (int*)p;                    p += cnt_b;
    float* nsrc = (float*)p;                  p += nsrc_b;
    int*   csr  = (int*)p;                    p += csr_b;
    unsigned short* xb = (unsigned short*)p;
    int*   ds_rep = csr;   // 8N ints alias the csr region (dead before fill)

    float* agg = out;      // alias output as aggregation buffer

    hipMemsetAsync(cnt, 0, cnt_b, stream);
    hipMemsetAsync(ds_rep, 0, (size_t)8 * N * sizeof(int), stream);

    const int EB = (E + 255) / 256;
    const int NB = (N + 255) / 256;

    k_deg_s <<<EB, 256, 0, stream>>>(src, ds_rep, E, N);
    k_norm_s<<<NB, 256, 0, stream>>>(ds_rep, nsrc, N);
    if (use_bf) {
        int n8 = N * D / 8;
        k_cvt<<<(n8 + 255) / 256, 256, 0, stream>>>(x, xb, n8);
    }
    const unsigned int* xbp = use_bf ? (const unsigned int*)xb : nullptr;
    if (use_rep) {
        k_fill<8, 16><<<EB, 256, 0, stream>>>(src, dst, cnt, csr, E, N);
        k_agg<8, 16><<<(N + 3) / 4, 256, 0, stream>>>(csr, cnt, nsrc, xbp, x, agg, N);
    } else {
        k_fill<1, 64><<<EB, 256, 0, stream>>>(src, dst, cnt, csr, E, N);
        k_agg<1, 64><<<(N + 3) / 4, 256, 0, stream>>>(csr, cnt, nsrc, xbp, x, agg, N);
    }
    k_gemm_norm<<<(N + 63) / 64, 256, 0, stream>>>(agg, x, W, bias, out, N);
}

// Round 7
// 368.993 us; speedup vs baseline: 1.1900x; 1.1900x over previous
//
#include <hip/hip_runtime.h>

#define D 128
#define FILL_PASSES 8

typedef __attribute__((ext_vector_type(8))) short short8;
typedef __attribute__((ext_vector_type(4))) float floatx4;

__device__ __forceinline__ short f32_bf16(float f) {
    unsigned u = __builtin_bit_cast(unsigned, f);
    u += 0x7fffu + ((u >> 16) & 1u);          // RNE
    return (short)(u >> 16);
}

// physical XCD id (hwreg 20 = HW_REG_XCC_ID, bits [3:0]) — wave-uniform
__device__ __forceinline__ int xcd_id() {
    return __builtin_amdgcn_s_getreg(20 | (3 << 11)) & 7;
}

// ---------------------------------------------------------------------------
// K1: out-degree histogram, physical-XCD replicas + workgroup-scope atomics
// (serviced in the local L2; exact under any block->XCD placement).
// ---------------------------------------------------------------------------
__global__ __launch_bounds__(256) void k_deg_s(const int* __restrict__ src,
                                               int* __restrict__ ds_rep,
                                               int E, int N) {
    int e = blockIdx.x * 256 + threadIdx.x;
    int r = xcd_id();
    if (e < E) {
        __hip_atomic_fetch_add(&ds_rep[r * N + src[e]], 1,
                               __ATOMIC_RELAXED, __HIP_MEMORY_SCOPE_WORKGROUP);
    }
}

// ---------------------------------------------------------------------------
// K2: reduce replicas -> norm_src
// ---------------------------------------------------------------------------
__global__ __launch_bounds__(256) void k_norm_s(const int* __restrict__ ds_rep,
                                                float* __restrict__ norm_src,
                                                int N) {
    int i = blockIdx.x * 256 + threadIdx.x;
    if (i < N) {
        int s = 0;
        #pragma unroll
        for (int r = 0; r < 8; ++r) s += ds_rep[r * N + i];
        norm_src[i] = rsqrtf((float)max(s, 1));
    }
}

// ---------------------------------------------------------------------------
// K3: x -> bf16 copy (halves k_agg gather traffic)
// ---------------------------------------------------------------------------
__global__ __launch_bounds__(256) void k_cvt(const float* __restrict__ x,
                                             unsigned short* __restrict__ xb,
                                             int n8) {
    int i = blockIdx.x * 256 + threadIdx.x;
    if (i < n8) {
        float4 a = ((const float4*)x)[2 * i];
        float4 b = ((const float4*)x)[2 * i + 1];
        short8 v;
        v[0] = f32_bf16(a.x); v[1] = f32_bf16(a.y);
        v[2] = f32_bf16(a.z); v[3] = f32_bf16(a.w);
        v[4] = f32_bf16(b.x); v[5] = f32_bf16(b.y);
        v[6] = f32_bf16(b.z); v[7] = f32_bf16(b.w);
        *(short8*)(xb + i * 8) = v;
    }
}

// ---------------------------------------------------------------------------
// K4: dst-tiled ELL fill. 8 internal passes over dst ranges keep the active
// store window (csr segment lines + counters) L2-resident per XCD, so each
// 64B line is written back once instead of once per store. R=8: XCD-local
// workgroup-scope slot allocators; R=1 fallback: agent-scope single alloc.
// No inter-pass sync needed: slot uniqueness is timing-independent.
// ---------------------------------------------------------------------------
template<int R, int SUBCAP>
__global__ __launch_bounds__(256) void k_fill_t(const int* __restrict__ src,
                                                const int* __restrict__ dst,
                                                int* __restrict__ cnt,
                                                int* __restrict__ csr,
                                                int E, int N) {
    const int r = (R == 8) ? xcd_id() : 0;
    const int stride = gridDim.x * 256;
    for (int p = 0; p < FILL_PASSES; ++p) {
        const int lo = (int)((long long)N * p / FILL_PASSES);
        const int hi = (int)((long long)N * (p + 1) / FILL_PASSES);
        const unsigned span = (unsigned)(hi - lo);
        for (int e = blockIdx.x * 256 + threadIdx.x; e < E; e += stride) {
            int d = dst[e];
            if ((unsigned)(d - lo) < span) {
                int slot;
                if (R == 8) {
                    slot = __hip_atomic_fetch_add(&cnt[r * N + d], 1,
                                                  __ATOMIC_RELAXED,
                                                  __HIP_MEMORY_SCOPE_WORKGROUP);
                } else {
                    slot = atomicAdd(&cnt[d], 1);
                }
                if (slot < SUBCAP) csr[d * (R * SUBCAP) + r * SUBCAP + slot] = src[e];
            }
        }
    }
}

// ---------------------------------------------------------------------------
// K5: per-node aggregation. One wave per node. Stage the node's R*SUBCAP ELL
// slots into LDS (coalesced), compact valid ids using the per-replica counts,
// then run a tight unroll-4 gather loop over the dense id list (wave-uniform
// ds_read broadcast) -> 8 gathers in flight, like the round-5 dense loop.
// ---------------------------------------------------------------------------
template<int R, int SUBCAP>
__global__ __launch_bounds__(256) void k_agg(const int* __restrict__ csr,
                                             const int* __restrict__ cnt,
                                             const float* __restrict__ norm_src,
                                             const unsigned int* __restrict__ xb,
                                             const float* __restrict__ x,
                                             float* __restrict__ agg, int N) {
    __shared__ int ids_s[4][R * SUBCAP];
    const int w = threadIdx.x >> 6;
    const int lane = threadIdx.x & 63;
    int n = blockIdx.x * 4 + w;
    if (n >= N) n = N - 1;              // duplicate work; keeps barriers uniform

    int cr[R], off[R + 1];
    int deg_true = 0;
    off[0] = 0;
    #pragma unroll
    for (int r = 0; r < R; ++r) {
        int c = cnt[r * N + n];
        deg_true += c;
        cr[r] = min(c, SUBCAP);
        off[r + 1] = off[r] + cr[r];
    }
    const int deg = off[R];

    // stage + compact: slot idx -> (replica idx>>log2(SUBCAP), pos idx&(SUBCAP-1))
    #pragma unroll
    for (int j = 0; j < (R * SUBCAP + 63) / 64; ++j) {
        int idx = lane + j * 64;
        if (idx < R * SUBCAP) {
            int rr = idx / SUBCAP;
            int ss = idx % SUBCAP;
            if (ss < cr[rr]) ids_s[w][off[rr] + ss] = csr[n * (R * SUBCAP) + idx];
        }
    }
    __syncthreads();

    const int* ids = ids_s[w];
    float ax = 0.f, ay = 0.f;
    if (xb) {
        int i = 0;
        for (; i + 4 <= deg; i += 4) {
            int s0 = ids[i];
            int s1 = ids[i + 1];
            int s2 = ids[i + 2];
            int s3 = ids[i + 3];
            float a0 = norm_src[s0];
            float a1 = norm_src[s1];
            float a2 = norm_src[s2];
            float a3 = norm_src[s3];
            unsigned u0 = xb[s0 * 64 + lane];
            unsigned u1 = xb[s1 * 64 + lane];
            unsigned u2 = xb[s2 * 64 + lane];
            unsigned u3 = xb[s3 * 64 + lane];
            ax = fmaf(__builtin_bit_cast(float, u0 << 16), a0, ax);
            ay = fmaf(__builtin_bit_cast(float, u0 & 0xffff0000u), a0, ay);
            ax = fmaf(__builtin_bit_cast(float, u1 << 16), a1, ax);
            ay = fmaf(__builtin_bit_cast(float, u1 & 0xffff0000u), a1, ay);
            ax = fmaf(__builtin_bit_cast(float, u2 << 16), a2, ax);
            ay = fmaf(__builtin_bit_cast(float, u2 & 0xffff0000u), a2, ay);
            ax = fmaf(__builtin_bit_cast(float, u3 << 16), a3, ax);
            ay = fmaf(__builtin_bit_cast(float, u3 & 0xffff0000u), a3, ay);
        }
        for (; i < deg; ++i) {
            int s0 = ids[i];
            float a0 = norm_src[s0];
            unsigned u0 = xb[s0 * 64 + lane];
            ax = fmaf(__builtin_bit_cast(float, u0 << 16), a0, ax);
            ay = fmaf(__builtin_bit_cast(float, u0 & 0xffff0000u), a0, ay);
        }
    } else {
        const float2* __restrict__ x2 = (const float2*)x;
        int i = 0;
        for (; i + 4 <= deg; i += 4) {
            int s0 = ids[i];
            int s1 = ids[i + 1];
            int s2 = ids[i + 2];
            int s3 = ids[i + 3];
            float a0 = norm_src[s0];
            float a1 = norm_src[s1];
            float a2 = norm_src[s2];
            float a3 = norm_src[s3];
            float2 v0 = x2[s0 * 64 + lane];
            float2 v1 = x2[s1 * 64 + lane];
            float2 v2 = x2[s2 * 64 + lane];
            float2 v3 = x2[s3 * 64 + lane];
            ax = fmaf(v0.x, a0, ax); ay = fmaf(v0.y, a0, ay);
            ax = fmaf(v1.x, a1, ax); ay = fmaf(v1.y, a1, ay);
            ax = fmaf(v2.x, a2, ax); ay = fmaf(v2.y, a2, ay);
            ax = fmaf(v3.x, a3, ax); ay = fmaf(v3.y, a3, ay);
        }
        for (; i < deg; ++i) {
            int s0 = ids[i];
            float a0 = norm_src[s0];
            float2 v0 = x2[s0 * 64 + lane];
            ax = fmaf(v0.x, a0, ax); ay = fmaf(v0.y, a0, ay);
        }
    }
    float nd = rsqrtf((float)max(deg_true, 1));
    ((float2*)agg)[n * 64 + lane] = make_float2(ax * nd, ay * nd);
}

// ---------------------------------------------------------------------------
// K6: MFMA bf16 GEMM + NodeNorm + relu + residual (unchanged).
// ---------------------------------------------------------------------------
#define WT_STRIDE 136
#define H_STRIDE  132

__global__ __launch_bounds__(256, 2) void k_gemm_norm(
    const float* __restrict__ agg,
    const float* __restrict__ x,
    const float* __restrict__ W,
    const float* __restrict__ bias,
    float* __restrict__ out, int N)
{
    __shared__ char raw[D * WT_STRIDE * 2];           // 34816 B >= 64*132*4
    short* Wt = (short*)raw;                          // Wt[c][k], bf16
    float* h  = (float*)raw;                          // h[64][H_STRIDE], after

    const int t = threadIdx.x;
    const int lane = t & 63;
    const int w = t >> 6;
    const int row0 = blockIdx.x * 64;

    #pragma unroll 4
    for (int i = 0; i < 64; ++i) {
        int idx = t + i * 256;
        int k = idx >> 7, c = idx & 127;
        Wt[c * WT_STRIDE + k] = f32_bf16(W[idx]);
    }
    __syncthreads();

    const int col16 = lane & 15;
    const int quad  = lane >> 4;
    int arow = row0 + w * 16 + col16;
    if (arow >= N) arow = N - 1;
    const float* aptr = agg + (long long)arow * D + quad * 8;

    floatx4 acc[8];
    #pragma unroll
    for (int c = 0; c < 8; ++c) {
        float b = bias[c * 16 + col16];
        acc[c] = (floatx4){b, b, b, b};
    }

    #pragma unroll
    for (int kc = 0; kc < 4; ++kc) {
        float4 a0 = *(const float4*)(aptr + kc * 32);
        float4 a1 = *(const float4*)(aptr + kc * 32 + 4);
        short8 af;
        af[0] = f32_bf16(a0.x); af[1] = f32_bf16(a0.y);
        af[2] = f32_bf16(a0.z); af[3] = f32_bf16(a0.w);
        af[4] = f32_bf16(a1.x); af[5] = f32_bf16(a1.y);
        af[6] = f32_bf16(a1.z); af[7] = f32_bf16(a1.w);
        const short* wbase = Wt + kc * 32 + quad * 8;
        #pragma unroll
        for (int c = 0; c < 8; ++c) {
            short8 bf = *(const short8*)(wbase + (c * 16 + col16) * WT_STRIDE);
            acc[c] = __builtin_amdgcn_mfma_f32_16x16x32_bf16(af, bf, acc[c], 0, 0, 0);
        }
    }
    __syncthreads();

    #pragma unroll
    for (int c = 0; c < 8; ++c) {
        #pragma unroll
        for (int i = 0; i < 4; ++i) {
            h[(w * 16 + quad * 4 + i) * H_STRIDE + c * 16 + col16] = acc[c][i];
        }
    }
    __syncthreads();

    const int row = t >> 2;
    const int part = t & 3;
    const float* hp = h + row * H_STRIDE + part * 32;
    float4 hv[8];
    float s = 0.f, ss = 0.f;
    #pragma unroll
    for (int i = 0; i < 8; ++i) {
        float4 v = *(const float4*)(hp + i * 4);
        hv[i] = v;
        s  += v.x + v.y + v.z + v.w;
        ss += v.x * v.x + v.y * v.y + v.z * v.z + v.w * v.w;
    }
    s += __shfl_xor(s, 1); ss += __shfl_xor(ss, 1);
    s += __shfl_xor(s, 2); ss += __shfl_xor(ss, 2);
    const float mean = s * (1.0f / 128.0f);
    const float var = ss * (1.0f / 128.0f) - mean * mean;
    const float inv = rsqrtf(var + 1e-5f);
    const int grow = row0 + row;
    if (grow < N) {
        const float* xp = x + (long long)grow * D + part * 32;
        float* op = out + (long long)grow * D + part * 32;
        #pragma unroll
        for (int i = 0; i < 8; ++i) {
            float4 v = hv[i];
            float4 xr = *(const float4*)(xp + i * 4);
            float4 o;
            o.x = fmaxf((v.x - mean) * inv, 0.f) + xr.x;
            o.y = fmaxf((v.y - mean) * inv, 0.f) + xr.y;
            o.z = fmaxf((v.z - mean) * inv, 0.f) + xr.z;
            o.w = fmaxf((v.w - mean) * inv, 0.f) + xr.w;
            *(float4*)(op + i * 4) = o;
        }
    }
}

// ---------------------------------------------------------------------------
extern "C" void kernel_launch(void* const* d_in, const int* in_sizes, int n_in,
                              void* d_out, int out_size, void* d_ws, size_t ws_size,
                              hipStream_t stream) {
    const float* x    = (const float*)d_in[0];
    const float* W    = (const float*)d_in[1];
    const float* bias = (const float*)d_in[2];
    const int*   src  = (const int*)d_in[3];
    const int*   dst  = (const int*)d_in[4];
    const int N = in_sizes[0] / D;
    const int E = in_sizes[3];
    float* out = (float*)d_out;

    const size_t AL = 255;
    size_t cnt_rep_b = (((size_t)8 * N * 4) + AL) & ~AL;
    size_t cnt_one_b = (((size_t)N * 4) + AL) & ~AL;
    size_t nsrc_b    = (((size_t)N * 4) + AL) & ~AL;
    size_t csr128_b  = (((size_t)N * 128 * 4) + AL) & ~AL;
    size_t csr64_b   = (((size_t)N * 64 * 4) + AL) & ~AL;
    size_t xb_b      = (((size_t)N * D * 2) + AL) & ~AL;

    bool use_rep, use_bf;
    if (ws_size >= cnt_rep_b + nsrc_b + csr128_b + xb_b)      { use_rep = true;  use_bf = true;  }
    else if (ws_size >= cnt_rep_b + nsrc_b + csr128_b)        { use_rep = true;  use_bf = false; }
    else if (ws_size >= cnt_one_b + nsrc_b + csr64_b + xb_b)  { use_rep = false; use_bf = true;  }
    else                                                      { use_rep = false; use_bf = false; }

    char* p = (char*)d_ws;
    size_t cnt_b = use_rep ? cnt_rep_b : cnt_one_b;
    size_t csr_b = use_rep ? csr128_b  : csr64_b;
    int*   cnt  = (int*)p;                    p += cnt_b;
    float* nsrc = (float*)p;                  p += nsrc_b;
    int*   csr  = (int*)p;                    p += csr_b;
    unsigned short* xb = (unsigned short*)p;
    int*   ds_rep = csr;   // 8N ints alias the csr region (dead before fill)

    float* agg = out;      // alias output as aggregation buffer

    hipMemsetAsync(cnt, 0, cnt_b, stream);
    hipMemsetAsync(ds_rep, 0, (size_t)8 * N * sizeof(int), stream);

    const int EB = (E + 255) / 256;
    const int NB = (N + 255) / 256;
    const int FB = 1024;   // fill blocks: 4/CU, co-resident, grid-stride

    k_deg_s <<<EB, 256, 0, stream>>>(src, ds_rep, E, N);
    k_norm_s<<<NB, 256, 0, stream>>>(ds_rep, nsrc, N);
    if (use_bf) {
        int n8 = N * D / 8;
        k_cvt<<<(n8 + 255) / 256, 256, 0, stream>>>(x, xb, n8);
    }
    const unsigned int* xbp = use_bf ? (const unsigned int*)xb : nullptr;
    if (use_rep) {
        k_fill_t<8, 16><<<FB, 256, 0, stream>>>(src, dst, cnt, csr, E, N);
        k_agg<8, 16><<<(N + 3) / 4, 256, 0, stream>>>(csr, cnt, nsrc, xbp, x, agg, N);
    } else {
        k_fill_t<1, 64><<<FB, 256, 0, stream>>>(src, dst, cnt, csr, E, N);
        k_agg<1, 64><<<(N + 3) / 4, 256, 0, stream>>>(csr, cnt, nsrc, xbp, x, agg, N);
    }
    k_gemm_norm<<<(N + 63) / 64, 256, 0, stream>>>(agg, x, W, bias, out, N);
}